// Round 2
// baseline (729.286 us; speedup 1.0000x reference)
//
#include <hip/hip_runtime.h>

// db4 reconstruction filters (hard-coded; match DB4_REC_LO/HI in reference)
#define G00 0.23037781330885523f
#define G01 0.7148465705525415f
#define G02 0.6308807679295904f
#define G03 -0.02798376941698385f
#define G04 -0.18703481171888114f
#define G05 0.030841381835986965f
#define G06 0.032883011666982945f
#define G07 -0.010597401784997278f

#define G10 -0.010597401784997278f
#define G11 -0.032883011666982945f
#define G12 0.030841381835986965f
#define G13 0.18703481171888114f
#define G14 -0.02798376941698385f
#define G15 -0.6308807679295904f
#define G16 0.7148465705525415f
#define G17 -0.23037781330885523f

// Generic 1D synthesis filter bank stage with periodic boundary.
// lo, hi: shape (B, n, inner) with per-B strides lo_bs / hi_bs (elements).
// out: contiguous (B, 2n, inner).
// out[b, j=2m+p, ii] = sum_t g0[2t+1-p]*lo[b, (m+p+1-t) mod n, ii]
//                    + sum_t g1[2t+1-p]*hi[b, (m+p+1-t) mod n, ii]
__global__ __launch_bounds__(256) void sfb1d_k(
    const float* __restrict__ lo, const float* __restrict__ hi,
    float* __restrict__ out,
    unsigned lo_bs, unsigned hi_bs,
    unsigned n, unsigned log_inner, unsigned log_2n, unsigned total)
{
    unsigned idx = blockIdx.x * 256u + threadIdx.x;
    if (idx >= total) return;

    unsigned inner_i = idx & ((1u << log_inner) - 1u);
    unsigned rest    = idx >> log_inner;
    unsigned j       = rest & ((1u << log_2n) - 1u);
    unsigned b       = rest >> log_2n;
    unsigned m = j >> 1;
    unsigned p = j & 1u;

    int mp = (int)(m + p);
    int i0 = mp + 1; if (i0 >= (int)n) i0 -= (int)n;
    int i1 = mp;     if (i1 >= (int)n) i1 -= (int)n;
    int i2 = mp - 1; if (i2 < 0) i2 += (int)n;
    int i3 = mp - 2; if (i3 < 0) i3 += (int)n;

    // coefficient tap k = 2t+1-p
    float a0 = p ? G00 : G01;
    float a1 = p ? G02 : G03;
    float a2 = p ? G04 : G05;
    float a3 = p ? G06 : G07;
    float c0 = p ? G10 : G11;
    float c1 = p ? G12 : G13;
    float c2 = p ? G14 : G15;
    float c3 = p ? G16 : G17;

    const float* lp = lo + (size_t)b * lo_bs + inner_i;
    const float* hp = hi + (size_t)b * hi_bs + inner_i;
    size_t st = (size_t)1 << log_inner;

    float acc = a0 * lp[(size_t)i0 * st]
              + a1 * lp[(size_t)i1 * st]
              + a2 * lp[(size_t)i2 * st]
              + a3 * lp[(size_t)i3 * st]
              + c0 * hp[(size_t)i0 * st]
              + c1 * hp[(size_t)i1 * st]
              + c2 * hp[(size_t)i2 * st]
              + c3 * hp[(size_t)i3 * st];

    out[idx] = acc;
}

static inline void launch_sfb(const float* lo, const float* hi, float* out,
                              unsigned lo_bs, unsigned hi_bs,
                              unsigned B, unsigned n, unsigned log_inner, unsigned log_2n,
                              hipStream_t stream)
{
    unsigned total = B << (log_2n + log_inner);
    dim3 grid((total + 255u) / 256u);
    sfb1d_k<<<grid, 256, 0, stream>>>(lo, hi, out, lo_bs, hi_bs, n, log_inner, log_2n, total);
}

extern "C" void kernel_launch(void* const* d_in, const int* in_sizes, int n_in,
                              void* d_out, int out_size, void* d_ws, size_t ws_size,
                              hipStream_t stream)
{
    const float* yl  = (const float*)d_in[0];   // (4,1,64,64,64)
    const float* yh1 = (const float*)d_in[1];   // (4,7,128,128,128)
    const float* yh2 = (const float*)d_in[2];   // (4,7,64,64,64)
    float* outf = (float*)d_out;                // (4,1,256,256,256)
    float* U    = (float*)d_ws;                 // needs 268,435,456 bytes

    const unsigned v1 = 64u * 64u * 64u;        // 262144
    const unsigned v2 = 128u * 128u * 128u;     // 2097152

    // ================= Level 1 (n=64 -> 128 per axis) =================
    // Stage 1 (axis D): pairs of subbands -> t_p (4,128,64,64), stored in d_out
    float* t1 = outf;                           // 4 x 2,097,152 floats
    for (int pr = 0; pr < 4; ++pr) {
        const float* lo = (pr == 0) ? yl : yh2 + (size_t)(2 * pr - 1) * v1;
        unsigned lo_bs  = (pr == 0) ? v1 : 7u * v1;
        const float* hi = yh2 + (size_t)(2 * pr) * v1;
        launch_sfb(lo, hi, t1 + (size_t)pr * 2097152u, lo_bs, 7u * v1,
                   4u, 64u, /*log_inner=*/12u, /*log_2n=*/7u, stream);
    }
    // Stage 2 (axis H): (t0,t1)->u0, (t2,t3)->u1, each (4,128,128,64), in ws
    float* ll1 = U;                             // 8,388,608 floats at U[0]
    float* u1  = U + 8388608u;                  // 2 x 4,194,304 floats
    for (int q = 0; q < 2; ++q) {
        launch_sfb(t1 + (size_t)(2 * q) * 2097152u,
                   t1 + (size_t)(2 * q + 1) * 2097152u,
                   u1 + (size_t)q * 4194304u,
                   4096u, 4096u, /*B=*/512u, 64u, /*log_inner=*/6u, 7u, stream);
    }
    // Stage 3 (axis W): (u0,u1) -> ll1 (4,128,128,128) at U[0]
    launch_sfb(u1, u1 + 4194304u, ll1, 64u, 64u,
               /*B=*/65536u, 64u, /*log_inner=*/0u, 7u, stream);

    // ================= Level 2 (n=128 -> 256 per axis) =================
    // Stage 1 (axis D): -> t_p (4,256,128,128), stored in d_out (fills it exactly)
    float* t2 = outf;                           // 4 x 16,777,216 floats
    for (int pr = 0; pr < 4; ++pr) {
        const float* lo = (pr == 0) ? ll1 : yh1 + (size_t)(2 * pr - 1) * v2;
        unsigned lo_bs  = (pr == 0) ? v2 : 7u * v2;
        const float* hi = yh1 + (size_t)(2 * pr) * v2;
        launch_sfb(lo, hi, t2 + (size_t)pr * 16777216u, lo_bs, 7u * v2,
                   4u, 128u, /*log_inner=*/14u, /*log_2n=*/8u, stream);
    }
    // Stage 2 (axis H): -> u_q (4,256,256,128), in ws (overwrites ll1 after use)
    float* u2 = U;                              // 2 x 33,554,432 floats
    for (int q = 0; q < 2; ++q) {
        launch_sfb(t2 + (size_t)(2 * q) * 16777216u,
                   t2 + (size_t)(2 * q + 1) * 16777216u,
                   u2 + (size_t)q * 33554432u,
                   16384u, 16384u, /*B=*/1024u, 128u, /*log_inner=*/7u, 8u, stream);
    }
    // Stage 3 (axis W): -> final output (4,1,256,256,256)
    launch_sfb(u2, u2 + 33554432u, outf, 128u, 128u,
               /*B=*/262144u, 128u, /*log_inner=*/0u, 8u, stream);
}

// Round 3
// 492.270 us; speedup vs baseline: 1.4815x; 1.4815x over previous
//
#include <hip/hip_runtime.h>

// db4 reconstruction filters
#define G00 0.23037781330885523f
#define G01 0.7148465705525415f
#define G02 0.6308807679295904f
#define G03 -0.02798376941698385f
#define G04 -0.18703481171888114f
#define G05 0.030841381835986965f
#define G06 0.032883011666982945f
#define G07 -0.010597401784997278f

#define G10 -0.010597401784997278f
#define G11 -0.032883011666982945f
#define G12 0.030841381835986965f
#define G13 0.18703481171888114f
#define G14 -0.02798376941698385f
#define G15 -0.6308807679295904f
#define G16 0.7148465705525415f
#define G17 -0.23037781330885523f

// ---------------------------------------------------------------------------
// Vectorized synthesis stage along a NON-contiguous axis.
// lo,hi viewed as float4: (B, n, inner4), out (B, 2n, inner4) contiguous.
// Each thread computes one float4 of output: 8 coalesced float4 loads.
// ---------------------------------------------------------------------------
__global__ __launch_bounds__(256) void sfb1d_vec4_k(
    const float4* __restrict__ lo, const float4* __restrict__ hi,
    float4* __restrict__ out,
    unsigned lo_bs4, unsigned hi_bs4,
    unsigned n, unsigned log_inner4, unsigned log_2n, unsigned total4)
{
    unsigned idx = blockIdx.x * 256u + threadIdx.x;
    if (idx >= total4) return;

    unsigned iv   = idx & ((1u << log_inner4) - 1u);
    unsigned rest = idx >> log_inner4;
    unsigned j    = rest & ((1u << log_2n) - 1u);
    unsigned b    = rest >> log_2n;
    unsigned m = j >> 1;
    unsigned p = j & 1u;

    int mp = (int)(m + p);
    int i0 = mp + 1; if (i0 >= (int)n) i0 -= (int)n;
    int i1 = mp;     if (i1 >= (int)n) i1 -= (int)n;
    int i2 = mp - 1; if (i2 < 0) i2 += (int)n;
    int i3 = mp - 2; if (i3 < 0) i3 += (int)n;

    float a0 = p ? G00 : G01;
    float a1 = p ? G02 : G03;
    float a2 = p ? G04 : G05;
    float a3 = p ? G06 : G07;
    float c0 = p ? G10 : G11;
    float c1 = p ? G12 : G13;
    float c2 = p ? G14 : G15;
    float c3 = p ? G16 : G17;

    const float4* lp = lo + (size_t)b * lo_bs4 + iv;
    const float4* hp = hi + (size_t)b * hi_bs4 + iv;
    size_t st = (size_t)1 << log_inner4;

    float4 L0 = lp[(size_t)i0 * st];
    float4 L1 = lp[(size_t)i1 * st];
    float4 L2 = lp[(size_t)i2 * st];
    float4 L3 = lp[(size_t)i3 * st];
    float4 H0 = hp[(size_t)i0 * st];
    float4 H1 = hp[(size_t)i1 * st];
    float4 H2 = hp[(size_t)i2 * st];
    float4 H3 = hp[(size_t)i3 * st];

    float4 r;
    r.x = a0*L0.x + a1*L1.x + a2*L2.x + a3*L3.x + c0*H0.x + c1*H1.x + c2*H2.x + c3*H3.x;
    r.y = a0*L0.y + a1*L1.y + a2*L2.y + a3*L3.y + c0*H0.y + c1*H1.y + c2*H2.y + c3*H3.y;
    r.z = a0*L0.z + a1*L1.z + a2*L2.z + a3*L3.z + c0*H0.z + c1*H1.z + c2*H2.z + c3*H3.z;
    r.w = a0*L0.w + a1*L1.w + a2*L2.w + a3*L3.w + c0*H0.w + c1*H1.w + c2*H2.w + c3*H3.w;

    out[idx] = r;
}

// ---------------------------------------------------------------------------
// Synthesis stage along the CONTIGUOUS (last) axis, via LDS chunking.
// lo,hi: dense (ROWS, n) row-major. out: dense (ROWS, 2n).
// Block = 256 threads; each block covers 256 output PAIRS = (256/n) rows.
// Stage 256 lo + 256 hi floats to LDS with float4 loads; each thread
// computes one (even,odd) output pair from 5 lo + 5 hi LDS reads.
// ---------------------------------------------------------------------------
__global__ __launch_bounds__(256) void sfb1d_last_k(
    const float4* __restrict__ lo4, const float4* __restrict__ hi4,
    float2* __restrict__ out2, unsigned log_n)
{
    __shared__ float ls[256];
    __shared__ float hs[256];

    unsigned t = threadIdx.x;
    unsigned chunk = blockIdx.x * 64u;
    if (t < 64u) {
        ((float4*)ls)[t] = lo4[chunk + t];
    } else if (t < 128u) {
        ((float4*)hs)[t - 64u] = hi4[chunk + (t - 64u)];
    }
    __syncthreads();

    unsigned n    = 1u << log_n;
    unsigned mask = n - 1u;
    unsigned r    = t >> log_n;       // local row within block
    unsigned m    = t & mask;         // pair index within row
    unsigned base = r << log_n;

    float lm2 = ls[base + ((m - 2u) & mask)];
    float lm1 = ls[base + ((m - 1u) & mask)];
    float l0  = ls[base + m];
    float lp1 = ls[base + ((m + 1u) & mask)];
    float lp2 = ls[base + ((m + 2u) & mask)];
    float hm2 = hs[base + ((m - 2u) & mask)];
    float hm1 = hs[base + ((m - 1u) & mask)];
    float h0  = hs[base + m];
    float hp1 = hs[base + ((m + 1u) & mask)];
    float hp2 = hs[base + ((m + 2u) & mask)];

    // p=0: taps g0[1],g0[3],g0[5],g0[7] at lo[m+1],lo[m],lo[m-1],lo[m-2] (+g1 on hi)
    float o0 = G01*lp1 + G03*l0 + G05*lm1 + G07*lm2
             + G11*hp1 + G13*h0 + G15*hm1 + G17*hm2;
    // p=1: taps g0[0],g0[2],g0[4],g0[6] at lo[m+2],lo[m+1],lo[m],lo[m-1]
    float o1 = G00*lp2 + G02*lp1 + G04*l0 + G06*lm1
             + G10*hp2 + G12*hp1 + G14*h0 + G16*hm1;

    out2[blockIdx.x * 256u + t] = make_float2(o0, o1);
}

// ---------------------------------------------------------------------------

static inline void launch_vec4(const float* lo, const float* hi, float* out,
                               unsigned lo_bs, unsigned hi_bs,
                               unsigned B, unsigned n, unsigned log_inner, unsigned log_2n,
                               hipStream_t stream)
{
    unsigned log_inner4 = log_inner - 2u;
    unsigned total4 = B << (log_2n + log_inner4);
    dim3 grid((total4 + 255u) / 256u);
    sfb1d_vec4_k<<<grid, 256, 0, stream>>>(
        (const float4*)lo, (const float4*)hi, (float4*)out,
        lo_bs / 4u, hi_bs / 4u, n, log_inner4, log_2n, total4);
}

static inline void launch_last(const float* lo, const float* hi, float* out,
                               unsigned rows, unsigned log_n, hipStream_t stream)
{
    unsigned n = 1u << log_n;
    unsigned blocks = (rows * n) / 256u;    // 256 pairs per block, exact
    sfb1d_last_k<<<dim3(blocks), 256, 0, stream>>>(
        (const float4*)lo, (const float4*)hi, (float2*)out, log_n);
}

extern "C" void kernel_launch(void* const* d_in, const int* in_sizes, int n_in,
                              void* d_out, int out_size, void* d_ws, size_t ws_size,
                              hipStream_t stream)
{
    const float* yl  = (const float*)d_in[0];   // (4,1,64,64,64)
    const float* yh1 = (const float*)d_in[1];   // (4,7,128,128,128)
    const float* yh2 = (const float*)d_in[2];   // (4,7,64,64,64)
    float* outf = (float*)d_out;                // (4,1,256,256,256)
    float* U    = (float*)d_ws;

    const unsigned v1 = 64u * 64u * 64u;        // 262144
    const unsigned v2 = 128u * 128u * 128u;     // 2097152

    // ================= Level 1 (n=64 -> 128 per axis) =================
    // Stage 1 (axis D): -> t_p (4,128,64,64) in d_out
    float* t1 = outf;
    for (int pr = 0; pr < 4; ++pr) {
        const float* lo = (pr == 0) ? yl : yh2 + (size_t)(2 * pr - 1) * v1;
        unsigned lo_bs  = (pr == 0) ? v1 : 7u * v1;
        const float* hi = yh2 + (size_t)(2 * pr) * v1;
        launch_vec4(lo, hi, t1 + (size_t)pr * 2097152u, lo_bs, 7u * v1,
                    4u, 64u, /*log_inner=*/12u, /*log_2n=*/7u, stream);
    }
    // Stage 2 (axis H): -> u_q (4,128,128,64) in ws
    float* ll1 = U;                      // 8,388,608 floats
    float* u1  = U + 8388608u;           // 2 x 4,194,304 floats
    for (int q = 0; q < 2; ++q) {
        launch_vec4(t1 + (size_t)(2 * q) * 2097152u,
                    t1 + (size_t)(2 * q + 1) * 2097152u,
                    u1 + (size_t)q * 4194304u,
                    4096u, 4096u, /*B=*/512u, 64u, /*log_inner=*/6u, 7u, stream);
    }
    // Stage 3 (axis W): (u0,u1) -> ll1 (4,128,128,128); 65536 rows of n=64
    launch_last(u1, u1 + 4194304u, ll1, 65536u, /*log_n=*/6u, stream);

    // ================= Level 2 (n=128 -> 256 per axis) =================
    // Stage 1 (axis D): -> t_p (4,256,128,128) in d_out
    float* t2 = outf;
    for (int pr = 0; pr < 4; ++pr) {
        const float* lo = (pr == 0) ? ll1 : yh1 + (size_t)(2 * pr - 1) * v2;
        unsigned lo_bs  = (pr == 0) ? v2 : 7u * v2;
        const float* hi = yh1 + (size_t)(2 * pr) * v2;
        launch_vec4(lo, hi, t2 + (size_t)pr * 16777216u, lo_bs, 7u * v2,
                    4u, 128u, /*log_inner=*/14u, /*log_2n=*/8u, stream);
    }
    // Stage 2 (axis H): -> u_q (4,256,256,128) in ws
    float* u2 = U;                       // 2 x 33,554,432 floats
    for (int q = 0; q < 2; ++q) {
        launch_vec4(t2 + (size_t)(2 * q) * 16777216u,
                    t2 + (size_t)(2 * q + 1) * 16777216u,
                    u2 + (size_t)q * 33554432u,
                    16384u, 16384u, /*B=*/1024u, 128u, /*log_inner=*/7u, 8u, stream);
    }
    // Stage 3 (axis W): -> final output; 262144 rows of n=128
    launch_last(u2, u2 + 33554432u, outf, 262144u, /*log_n=*/7u, stream);
}

// Round 4
// 276.295 us; speedup vs baseline: 2.6395x; 1.7817x over previous
//
#include <hip/hip_runtime.h>

typedef float f32x4 __attribute__((ext_vector_type(4)));

// db4 reconstruction filters
#define G00 0.23037781330885523f
#define G01 0.7148465705525415f
#define G02 0.6308807679295904f
#define G03 -0.02798376941698385f
#define G04 -0.18703481171888114f
#define G05 0.030841381835986965f
#define G06 0.032883011666982945f
#define G07 -0.010597401784997278f

#define G10 -0.010597401784997278f
#define G11 -0.032883011666982945f
#define G12 0.030841381835986965f
#define G13 0.18703481171888114f
#define G14 -0.02798376941698385f
#define G15 -0.6308807679295904f
#define G16 0.7148465705525415f
#define G17 -0.23037781330885523f

// ---------------------------------------------------------------------------
// Stage 1 (axis D), all 4 subband pairs fused via blockIdx.z.
// Each thread computes an output PAIR (j=2m, 2m+1) for one float4 of inner:
// 10 f32x4 loads, 2 f32x4 stores.
// t layout: (pr, b, 2N, N, N), pr-major then batch.
// ---------------------------------------------------------------------------
template<int LOGN>
__global__ __launch_bounds__(256) void s1_k(
    const float* __restrict__ ll, const float* __restrict__ yh,
    float* __restrict__ t, int b0)
{
    constexpr int N = 1 << LOGN;
    constexpr int LOGI4 = 2 * LOGN - 2;
    constexpr unsigned I4 = 1u << LOGI4;      // inner float4 count = N*N/4
    constexpr size_t V = (size_t)N * N * N;

    unsigned gid = blockIdx.x * 256u + threadIdx.x;
    unsigned iv = gid & (I4 - 1u);
    int m = (int)(gid >> LOGI4);              // [0, N), grid.x exact
    int b = b0 + (int)blockIdx.y;
    int pr = (int)blockIdx.z;

    const float* lo = (pr == 0) ? (ll + (size_t)b * V)
                                : (yh + (size_t)b * 7 * V + (size_t)(2 * pr - 1) * V);
    const float* hi = yh + (size_t)b * 7 * V + (size_t)(2 * pr) * V;

    const f32x4* lp = (const f32x4*)lo + iv;
    const f32x4* hp = (const f32x4*)hi + iv;

    int im2 = m - 2; if (im2 < 0) im2 += N;
    int im1 = m - 1; if (im1 < 0) im1 += N;
    int ip1 = m + 1; if (ip1 >= N) ip1 -= N;
    int ip2 = m + 2; if (ip2 >= N) ip2 -= N;

    f32x4 Lm2 = lp[(size_t)im2 * I4];
    f32x4 Lm1 = lp[(size_t)im1 * I4];
    f32x4 L0  = lp[(size_t)m   * I4];
    f32x4 Lp1 = lp[(size_t)ip1 * I4];
    f32x4 Lp2 = lp[(size_t)ip2 * I4];
    f32x4 Hm2 = hp[(size_t)im2 * I4];
    f32x4 Hm1 = hp[(size_t)im1 * I4];
    f32x4 H0  = hp[(size_t)m   * I4];
    f32x4 Hp1 = hp[(size_t)ip1 * I4];
    f32x4 Hp2 = hp[(size_t)ip2 * I4];

    f32x4 o0 = G01*Lp1 + G03*L0 + G05*Lm1 + G07*Lm2
             + G11*Hp1 + G13*H0 + G15*Hm1 + G17*Hm2;
    f32x4 o1 = G00*Lp2 + G02*Lp1 + G04*L0 + G06*Lm1
             + G10*Hp2 + G12*Hp1 + G14*H0 + G16*Hm1;

    f32x4* tp = (f32x4*)(t + ((size_t)pr * 4 + b) * 2 * V) + iv;
    tp[(size_t)(2 * m)     * I4] = o0;
    tp[(size_t)(2 * m + 1) * I4] = o1;
}

// ---------------------------------------------------------------------------
// Fused stages 2+3 (axes H then W) in LDS.
// Block: one (b, d) slice, 32 output H-rows (tile), full W.
// Loads 4 subband tiles (20 halo rows x N) -> H-synth into ul[2][32][N]
// -> W-synth -> 32 rows x 2N floats of final output.
// ---------------------------------------------------------------------------
template<int LOGN, bool NT>
__global__ __launch_bounds__(512) void s23_k(
    const float* __restrict__ t, float* __restrict__ out, int b0)
{
    constexpr int N = 1 << LOGN;
    constexpr int N4 = N / 4;
    constexpr size_t V = (size_t)N * N * N;

    __shared__ f32x4 tl[4][20][N4];
    __shared__ __align__(16) float ul[2][32][N];

    const int tid  = threadIdx.x;
    const int tile = blockIdx.x;              // output H rows [32*tile, 32*tile+32)
    const int d    = blockIdx.y;              // [0, 2N)
    const int b    = b0 + (int)blockIdx.z;

    // ---- load 4 subband tiles: global rows (16*tile - 2 + r) mod N
    const int h0in = 16 * tile - 2;
    for (int q = tid; q < 4 * 20 * N4; q += 512) {
        int s   = q / (20 * N4);
        int rem = q - s * (20 * N4);
        int r   = rem / N4;
        int w4  = rem - r * N4;
        int hr  = h0in + r;
        if (hr < 0) hr += N;
        if (hr >= N) hr -= N;
        const f32x4* src = (const f32x4*)(t + ((size_t)s * 4 + b) * 2 * V
                                            + (size_t)d * N * N + (size_t)hr * N);
        tl[s][r][w4] = src[w4];
    }
    __syncthreads();

    // ---- H synthesis: ul[q][hl][w] for hl in [0,32), local rows ro-t in [0,20)
    for (int e = tid; e < 2 * 32 * N4; e += 512) {
        int w4   = e & (N4 - 1);
        int rest = e >> (LOGN - 2);
        int hl   = rest & 31;
        int qq   = rest >> 5;
        int ml = hl >> 1, p = hl & 1;
        int ro = ml + p + 3;
        float a0 = p ? G00 : G01, a1 = p ? G02 : G03;
        float a2 = p ? G04 : G05, a3 = p ? G06 : G07;
        float c0 = p ? G10 : G11, c1 = p ? G12 : G13;
        float c2 = p ? G14 : G15, c3 = p ? G16 : G17;
        int s0 = 2 * qq, s1 = 2 * qq + 1;
        f32x4 acc = a0 * tl[s0][ro][w4] + a1 * tl[s0][ro - 1][w4]
                  + a2 * tl[s0][ro - 2][w4] + a3 * tl[s0][ro - 3][w4]
                  + c0 * tl[s1][ro][w4] + c1 * tl[s1][ro - 1][w4]
                  + c2 * tl[s1][ro - 2][w4] + c3 * tl[s1][ro - 3][w4];
        *(f32x4*)&ul[qq][hl][w4 * 4] = acc;
    }
    __syncthreads();

    // ---- W synthesis + store: 4 outputs (2 pairs) per iter
    float* orow_base = out + (((size_t)b * (2 * N) + d) * (2 * N) + (size_t)32 * tile) * (2 * N);
    for (int e = tid; e < 32 * (N / 2); e += 512) {
        int mw2 = e & (N / 2 - 1);
        int hl  = e >> (LOGN - 1);
        int mw  = mw2 * 2;
        const float* u0 = ul[0][hl];
        const float* u1 = ul[1][hl];
        int mm2 = (mw - 2) & (N - 1), mm1 = (mw - 1) & (N - 1);
        int mp1 = (mw + 1) & (N - 1), mp2 = (mw + 2) & (N - 1), mp3 = (mw + 3) & (N - 1);
        float u0m2 = u0[mm2], u0m1 = u0[mm1], u00 = u0[mw];
        float u0p1 = u0[mp1], u0p2 = u0[mp2], u0p3 = u0[mp3];
        float u1m2 = u1[mm2], u1m1 = u1[mm1], u10 = u1[mw];
        float u1p1 = u1[mp1], u1p2 = u1[mp2], u1p3 = u1[mp3];
        f32x4 o;
        o.x = G01*u0p1 + G03*u00  + G05*u0m1 + G07*u0m2
            + G11*u1p1 + G13*u10  + G15*u1m1 + G17*u1m2;
        o.y = G00*u0p2 + G02*u0p1 + G04*u00  + G06*u0m1
            + G10*u1p2 + G12*u1p1 + G14*u10  + G16*u1m1;
        o.z = G01*u0p2 + G03*u0p1 + G05*u00  + G07*u0m1
            + G11*u1p2 + G13*u1p1 + G15*u10  + G17*u1m1;
        o.w = G00*u0p3 + G02*u0p2 + G04*u0p1 + G06*u00
            + G10*u1p3 + G12*u1p2 + G14*u1p1 + G16*u10;
        f32x4* dst = (f32x4*)(orow_base + (size_t)hl * (2 * N)) + mw2;
        if (NT) __builtin_nontemporal_store(o, dst);
        else    *dst = o;
    }
}

// ---------------------------------------------------------------------------

extern "C" void kernel_launch(void* const* d_in, const int* in_sizes, int n_in,
                              void* d_out, int out_size, void* d_ws, size_t ws_size,
                              hipStream_t stream)
{
    const float* yl  = (const float*)d_in[0];   // (4,1,64,64,64)
    const float* yh1 = (const float*)d_in[1];   // (4,7,128,128,128)
    const float* yh2 = (const float*)d_in[2];   // (4,7,64,64,64)
    float* outf = (float*)d_out;                // (4,1,256,256,256) = 67,108,864 floats
    float* W    = (float*)d_ws;                 // >= 268,435,456 bytes

    // Memory map:
    //   t1  : outf[0 .. 8,388,608)              (level-1 D-synth, 33.5 MB)
    //   ll1 : outf[58,720,256 .. 67,108,864)    (tail 33.5 MB; inside b=3 output
    //         region, which is only written by the LAST s23 launch, after its
    //         consumer s1(b=3) has already read ll1)
    //   t2  : W[0 .. 67,108,864)                (level-2 D-synth, full 268 MB ws)
    float* t1  = outf;
    float* ll1 = outf + 58720256u;
    float* t2  = W;

    // ---------------- Level 1 (n=64 -> 128) ----------------
    // S1: grid.x = (64 * 1024)/256 = 256, all 4 batches, 4 subband pairs
    s1_k<6><<<dim3(256, 4, 4), 256, 0, stream>>>(yl, yh2, t1, 0);
    // S23: tiles = 128/32 = 4, d = 128, b = 4; cached stores (ll1 re-read)
    s23_k<6, false><<<dim3(4, 128, 4), 512, 0, stream>>>(t1, ll1, 0);

    // ---------------- Level 2 (n=128 -> 256), per-batch for L3 reuse -------
    for (int b = 0; b < 4; ++b) {
        // S1: grid.x = (128 * 4096)/256 = 2048, one batch, 4 subband pairs
        s1_k<7><<<dim3(2048, 1, 4), 256, 0, stream>>>(ll1, yh1, t2, b);
        // S23: tiles = 256/32 = 8, d = 256; nontemporal final stores
        s23_k<7, true><<<dim3(8, 256, 1), 512, 0, stream>>>(t2, outf, b);
    }
}

// Round 5
// 224.012 us; speedup vs baseline: 3.2556x; 1.2334x over previous
//
#include <hip/hip_runtime.h>

typedef float f32x4 __attribute__((ext_vector_type(4)));

// db4 reconstruction filters
#define G00 0.23037781330885523f
#define G01 0.7148465705525415f
#define G02 0.6308807679295904f
#define G03 -0.02798376941698385f
#define G04 -0.18703481171888114f
#define G05 0.030841381835986965f
#define G06 0.032883011666982945f
#define G07 -0.010597401784997278f

#define G10 -0.010597401784997278f
#define G11 -0.032883011666982945f
#define G12 0.030841381835986965f
#define G13 0.18703481171888114f
#define G14 -0.02798376941698385f
#define G15 -0.6308807679295904f
#define G16 0.7148465705525415f
#define G17 -0.23037781330885523f

// ---------------------------------------------------------------------------
// Fully-fused 3-axis inverse DWT level.
// Block = one output d-plane (blockIdx.y), 32 output h-rows (blockIdx.x),
// full W; batch via blockIdx.z + b0.
// Phase A: D-synthesis from the 8 subbands directly (global reads; the
//          4 D-plane indices are block-uniform) -> tl[4][20][N/4] in LDS.
// Phase B: H-synthesis -> ul[2][32][N] in LDS.
// Phase C: W-synthesis -> 32 rows x 2N floats of output (NT for final level).
// ---------------------------------------------------------------------------
template<int LOGN, bool NT>
__global__ __launch_bounds__(512) void idwt3_fused_k(
    const float* __restrict__ ll, const float* __restrict__ yh,
    float* __restrict__ out, int b0)
{
    constexpr int N = 1 << LOGN;
    constexpr int N4 = N / 4;
    constexpr int LOGN4 = LOGN - 2;
    constexpr size_t V = (size_t)N * N * N;

    __shared__ f32x4 tl[4][20][N4];
    __shared__ __align__(16) float ul[2][32][N];

    const int tid  = threadIdx.x;
    const int tile = blockIdx.x;              // output h rows [32*tile, 32*tile+32)
    const int d    = blockIdx.y;              // output d-plane in [0, 2N)
    const int b    = b0 + (int)blockIdx.z;

    // ---- D-synth parameters (block-uniform): out[d=2m+p] taps planes
    // (m+p+1-tt) mod N with coeffs below, tt = 0..3.
    const int m = d >> 1, p = d & 1;
    const int P0 = (m + p + 1) & (N - 1);
    const int P1 = (m + p) & (N - 1);
    const int P2 = (m + p - 1 + N) & (N - 1);
    const int P3 = (m + p - 2 + N) & (N - 1);
    const float a0 = p ? G00 : G01, a1 = p ? G02 : G03;
    const float a2 = p ? G04 : G05, a3 = p ? G06 : G07;
    const float c0 = p ? G10 : G11, c1 = p ? G12 : G13;
    const float c2 = p ? G14 : G15, c3 = p ? G16 : G17;

    const int h0in = 16 * tile - 2;           // first halo h-row (wrapped)

    // ---- Phase A: t_pr(d, hr, :) for 20 halo rows, 4 subband pairs.
    // Subband s = qD + 2*qH + 4*qW; pair pr=(qH,qW): lo = y_{2pr}, hi = y_{2pr+1};
    // y_0 = ll, y_s = yh[s-1] for s >= 1.
    const float* yb = yh + (size_t)b * 7 * V;
    #pragma unroll
    for (int pr = 0; pr < 4; ++pr) {
        const float* lo = (pr == 0) ? (ll + (size_t)b * V)
                                    : (yb + (size_t)(2 * pr - 1) * V);
        const float* hi = yb + (size_t)(2 * pr) * V;
        const f32x4* lo0 = (const f32x4*)(lo + (size_t)P0 * N * N);
        const f32x4* lo1 = (const f32x4*)(lo + (size_t)P1 * N * N);
        const f32x4* lo2 = (const f32x4*)(lo + (size_t)P2 * N * N);
        const f32x4* lo3 = (const f32x4*)(lo + (size_t)P3 * N * N);
        const f32x4* hi0 = (const f32x4*)(hi + (size_t)P0 * N * N);
        const f32x4* hi1 = (const f32x4*)(hi + (size_t)P1 * N * N);
        const f32x4* hi2 = (const f32x4*)(hi + (size_t)P2 * N * N);
        const f32x4* hi3 = (const f32x4*)(hi + (size_t)P3 * N * N);
        for (int e = tid; e < 20 * N4; e += 512) {
            int w4 = e & (N4 - 1);
            int r  = e >> LOGN4;
            int hr = h0in + r;
            if (hr < 0) hr += N;
            if (hr >= N) hr -= N;
            int off = hr * N4 + w4;
            tl[pr][r][w4] = a0 * lo0[off] + a1 * lo1[off]
                          + a2 * lo2[off] + a3 * lo3[off]
                          + c0 * hi0[off] + c1 * hi1[off]
                          + c2 * hi2[off] + c3 * hi3[off];
        }
    }
    __syncthreads();

    // ---- Phase B: H synthesis -> ul[qW][hl][w], hl in [0,32)
    for (int e = tid; e < 2 * 32 * N4; e += 512) {
        int w4   = e & (N4 - 1);
        int rest = e >> LOGN4;
        int hl   = rest & 31;
        int qq   = rest >> 5;
        int ml = hl >> 1, pp = hl & 1;
        int ro = ml + pp + 3;                 // local row (global m_h + p + 1 shifted by halo)
        float b0c = pp ? G00 : G01, b1c = pp ? G02 : G03;
        float b2c = pp ? G04 : G05, b3c = pp ? G06 : G07;
        float d0c = pp ? G10 : G11, d1c = pp ? G12 : G13;
        float d2c = pp ? G14 : G15, d3c = pp ? G16 : G17;
        int s0 = 2 * qq, s1 = 2 * qq + 1;
        f32x4 acc = b0c * tl[s0][ro][w4] + b1c * tl[s0][ro - 1][w4]
                  + b2c * tl[s0][ro - 2][w4] + b3c * tl[s0][ro - 3][w4]
                  + d0c * tl[s1][ro][w4] + d1c * tl[s1][ro - 1][w4]
                  + d2c * tl[s1][ro - 2][w4] + d3c * tl[s1][ro - 3][w4];
        *(f32x4*)&ul[qq][hl][w4 * 4] = acc;
    }
    __syncthreads();

    // ---- Phase C: W synthesis + store (4 outputs = 2 pairs per iter)
    float* orow_base = out + (((size_t)b * (2 * N) + d) * (2 * N) + (size_t)32 * tile) * (2 * N);
    for (int e = tid; e < 32 * (N / 2); e += 512) {
        int mw2 = e & (N / 2 - 1);
        int hl  = e >> (LOGN - 1);
        int mw  = mw2 * 2;
        const float* u0 = ul[0][hl];
        const float* u1 = ul[1][hl];
        int mm2 = (mw - 2) & (N - 1), mm1 = (mw - 1) & (N - 1);
        int mp1 = (mw + 1) & (N - 1), mp2 = (mw + 2) & (N - 1), mp3 = (mw + 3) & (N - 1);
        float u0m2 = u0[mm2], u0m1 = u0[mm1], u00 = u0[mw];
        float u0p1 = u0[mp1], u0p2 = u0[mp2], u0p3 = u0[mp3];
        float u1m2 = u1[mm2], u1m1 = u1[mm1], u10 = u1[mw];
        float u1p1 = u1[mp1], u1p2 = u1[mp2], u1p3 = u1[mp3];
        f32x4 o;
        o.x = G01*u0p1 + G03*u00  + G05*u0m1 + G07*u0m2
            + G11*u1p1 + G13*u10  + G15*u1m1 + G17*u1m2;
        o.y = G00*u0p2 + G02*u0p1 + G04*u00  + G06*u0m1
            + G10*u1p2 + G12*u1p1 + G14*u10  + G16*u1m1;
        o.z = G01*u0p2 + G03*u0p1 + G05*u00  + G07*u0m1
            + G11*u1p2 + G13*u1p1 + G15*u10  + G17*u1m1;
        o.w = G00*u0p3 + G02*u0p2 + G04*u0p1 + G06*u00
            + G10*u1p3 + G12*u1p2 + G14*u1p1 + G16*u10;
        f32x4* dst = (f32x4*)(orow_base + (size_t)hl * (2 * N)) + mw2;
        if (NT) __builtin_nontemporal_store(o, dst);
        else    *dst = o;
    }
}

// ---------------------------------------------------------------------------

extern "C" void kernel_launch(void* const* d_in, const int* in_sizes, int n_in,
                              void* d_out, int out_size, void* d_ws, size_t ws_size,
                              hipStream_t stream)
{
    const float* yl  = (const float*)d_in[0];   // (4,1,64,64,64)
    const float* yh1 = (const float*)d_in[1];   // (4,7,128,128,128)
    const float* yh2 = (const float*)d_in[2];   // (4,7,64,64,64)
    float* outf = (float*)d_out;                // (4,1,256,256,256)
    float* ll1  = (float*)d_ws;                 // (4,128,128,128) = 33.5 MB scratch

    // ---- Level 1 (n=64 -> 128): fused, all batches; ll1 cached (re-read below)
    idwt3_fused_k<6, false><<<dim3(4, 128, 4), 512, 0, stream>>>(yl, yh2, ll1, 0);

    // ---- Level 2 (n=128 -> 256): fused, per-batch for L3 input residency;
    //      nontemporal final stores
    for (int b = 0; b < 4; ++b) {
        idwt3_fused_k<7, true><<<dim3(8, 256, 1), 512, 0, stream>>>(ll1, yh1, outf, b);
    }
}